// Round 2
// baseline (467.603 us; speedup 1.0000x reference)
//
#include <hip/hip_runtime.h>

// LIF spike scan, LDS-staged for coalescing.
// x/out: [524288 neurons][T=100] fp32 row-major.
//
// R0 lesson: one-thread-per-neuron with direct global access = 64 cache lines
// per wave load (400B lane stride) -> TA serialization, 2.4 TB/s, 186 us.
// R1: block owns 256 consecutive neurons; time is processed in 5 chunks of 20.
// Each chunk: cooperative float4 loads (80B contiguous segments per row) into
// LDS [256][21] (pad 21: odd stride, conflict-free row walk), per-thread scan
// of 20 steps with carry (mem,spike) in registers, spikes written back in
// place, then coalesced float4 writeout. LDS = 21.5 KB -> 8 blocks/CU.
//
// Numerics: must match numpy's separately-rounded mem = (mem*DECAY)*(1-spike)+xi
// exactly (output is a threshold compare; 1-ulp FMA contraction flips spikes).

#define THRESH 0.5f
#define DECAY  0.2f

constexpr int T   = 100;
constexpr int TC  = 20;                     // time steps per chunk
constexpr int NC  = T / TC;                 // 5 chunks
constexpr int NB  = 256;                    // neurons per block
constexpr int PAD = TC + 1;                 // LDS row stride 21 (coprime w/ 32)
constexpr int F4_PER_ROW   = TC / 4;        // 5
constexpr int F4_PER_CHUNK = NB * F4_PER_ROW;   // 1280
constexpr int QITERS = F4_PER_CHUNK / 256;  // 5 float4 ops per thread per chunk

__global__ __launch_bounds__(256) void lif_kernel(const float* __restrict__ x,
                                                  float* __restrict__ out) {
    __shared__ float tile[NB * PAD];
    const int tid = threadIdx.x;
    const size_t blockBase = (size_t)blockIdx.x * NB * T;

    // Per-thread staging map (same every chunk): float4 #f -> (row r, col j)
    int rq[QITERS], jq[QITERS];
#pragma unroll
    for (int q = 0; q < QITERS; ++q) {
        int f = q * 256 + tid;
        rq[q] = f / F4_PER_ROW;
        jq[q] = f % F4_PER_ROW;
    }

    float mem = 0.0f, spike = 0.0f;

    for (int c = 0; c < NC; ++c) {
        // ---- load: global (80B row segments) -> LDS rows ----
#pragma unroll
        for (int q = 0; q < QITERS; ++q) {
            const float4 v = *reinterpret_cast<const float4*>(
                x + blockBase + (size_t)rq[q] * T + c * TC + jq[q] * 4);
            float* dst = &tile[rq[q] * PAD + jq[q] * 4];
            dst[0] = v.x; dst[1] = v.y; dst[2] = v.z; dst[3] = v.w;
        }
        __syncthreads();

        // ---- scan: thread `tid` advances its neuron 20 steps ----
        float* row = &tile[tid * PAD];
#pragma unroll
        for (int t = 0; t < TC; ++t) {
            float u = row[t];
            mem = __fadd_rn(__fmul_rn(__fmul_rn(mem, DECAY),
                                      __fsub_rn(1.0f, spike)), u);
            spike = (mem > THRESH) ? 1.0f : 0.0f;
            row[t] = spike;
        }
        __syncthreads();

        // ---- writeout: LDS rows -> global float4 (coalesced like load) ----
#pragma unroll
        for (int q = 0; q < QITERS; ++q) {
            const float* src = &tile[rq[q] * PAD + jq[q] * 4];
            float4 v;
            v.x = src[0]; v.y = src[1]; v.z = src[2]; v.w = src[3];
            *reinterpret_cast<float4*>(
                out + blockBase + (size_t)rq[q] * T + c * TC + jq[q] * 4) = v;
        }
        __syncthreads();  // protect tile before next chunk's load
    }
}

extern "C" void kernel_launch(void* const* d_in, const int* in_sizes, int n_in,
                              void* d_out, int out_size, void* d_ws, size_t ws_size,
                              hipStream_t stream) {
    const float* x   = (const float*)d_in[0];
    float*       out = (float*)d_out;

    int n_neurons = in_sizes[0] / T;          // 524288
    int grid = n_neurons / NB;                // 2048 blocks, exact

    lif_kernel<<<grid, NB, 0, stream>>>(x, out);
}

// Round 3
// 344.290 us; speedup vs baseline: 1.3582x; 1.3582x over previous
//
#include <hip/hip_runtime.h>

// LIF spike scan, R2: whole-row wave tiles with fully-coalesced flat I/O.
// x/out: [524288 neurons][T=100] fp32 row-major.
//
// R0: direct per-thread row streaming -> 64 lines/wave-load, 2.4 TB/s.
// R1: time-chunked LDS staging -> only 80-B segments, still 2.3 TB/s, barriers.
// R2 insight: a wave's 64 rows are one CONTIGUOUS 25.6-KB region. Load it
// flat: 25 x (lane l takes float4 #(k*64+l)) = perfect 1024-B wave
// transactions. Transpose via per-wave LDS tile [25 timegroups][65 pad] f4:
//   - staging scatter/gather: 8-way b128 conflicts, ~50 ops/wave, cheap
//   - scan access tile[g*65+lane]: consecutive lanes/consecutive 16B, free
// 64-thread blocks (1 wave): barriers degenerate to waitcnt; 26 KB LDS ->
// 6 waves/CU; in-flight bytes >> Little's-law need for 6.3 TB/s.
//
// Numerics: output is a threshold compare; must match numpy's rounding
// sequence mem=(mem*DECAY)*(1-spike)+xi bit-exactly. Since spike is exactly
// 0.0 or 1.0: mul by 1.0 and add of -0.0 are rounding-exact identities, so
//   mem = spike ? xi : __fadd_rn(__fmul_rn(mem, DECAY), xi)
// is bit-identical. __f*_rn intrinsics are never FMA-contracted.

#define THRESH 0.5f
#define DECAY  0.2f

constexpr int T        = 100;
constexpr int ROWS     = 64;            // neurons per wave/block
constexpr int F4_ROW   = T / 4;         // 25 float4 per row
constexpr int F4_TILE  = ROWS * F4_ROW; // 1600 float4 per tile (25.6 KB)
constexpr int K        = F4_TILE / 64;  // 25 coalesced wave-loads
constexpr int STRIDE   = ROWS + 1;      // 65 f4: LDS row stride, de-conflicts

__global__ __launch_bounds__(64) void lif_kernel(const float* __restrict__ x,
                                                 float* __restrict__ out) {
    __shared__ float4 tile[F4_ROW * STRIDE];  // [g][r], 26 KB

    const int l = threadIdx.x;
    const size_t base = (size_t)blockIdx.x * F4_TILE;
    const float4* src = reinterpret_cast<const float4*>(x) + base;
    float4*       dst = reinterpret_cast<float4*>(out) + base;

    // ---- stage in: 25 fully-coalesced 1024-B loads, scatter to [g][r] ----
    float4 v[K];
#pragma unroll
    for (int k = 0; k < K; ++k) v[k] = src[k * 64 + l];
#pragma unroll
    for (int k = 0; k < K; ++k) {
        int flat = k * 64 + l;
        int r = flat / F4_ROW;          // magic-mul, cheap
        int g = flat % F4_ROW;
        tile[g * STRIDE + r] = v[k];
    }
    __syncthreads();  // single-wave block: compiles to waitcnt, no s_barrier

    // ---- scan: lane l owns neuron row l; conflict-free tile[g][l] ----
    float mem = 0.0f, spike = 0.0f;
#pragma unroll
    for (int g = 0; g < F4_ROW; ++g) {
        float4 u = tile[g * STRIDE + l];
        float4 s;
#define STEP(comp)                                                            \
        {                                                                     \
            float leak = __fmul_rn(mem, DECAY);                               \
            mem = (spike != 0.0f) ? u.comp : __fadd_rn(leak, u.comp);         \
            spike = (mem > THRESH) ? 1.0f : 0.0f;                             \
            s.comp = spike;                                                   \
        }
        STEP(x) STEP(y) STEP(z) STEP(w)
#undef STEP
        tile[g * STRIDE + l] = s;  // in-place, conflict-free
    }
    __syncthreads();

    // ---- write out: gather from [g][r], 25 coalesced 1024-B stores ----
#pragma unroll
    for (int k = 0; k < K; ++k) {
        int flat = k * 64 + l;
        int r = flat / F4_ROW;
        int g = flat % F4_ROW;
        dst[k * 64 + l] = tile[g * STRIDE + r];
    }
}

extern "C" void kernel_launch(void* const* d_in, const int* in_sizes, int n_in,
                              void* d_out, int out_size, void* d_ws, size_t ws_size,
                              hipStream_t stream) {
    const float* x   = (const float*)d_in[0];
    float*       out = (float*)d_out;

    int n_neurons = in_sizes[0] / T;      // 524288
    int grid = n_neurons / ROWS;          // 8192 blocks of 64 threads

    lif_kernel<<<grid, ROWS, 0, stream>>>(x, out);
}